// Round 7
// baseline (34631.186 us; speedup 1.0000x reference)
//
#include <hip/hip_runtime.h>
#include <math.h>

#define B_N 64
#define T_N 3072
#define FIN 128
#define TP 1024      // conv output length
#define COUT 64
#define HID 256
#define G4 1024      // 4*HID
#define OUT_N 10
#define NCHUNK 24
#define CHUNK_T (T_N / NCHUNK)   // 128
#define NBLK 4       // blocks per batch (each owns 64 hidden units)

// v7 LSTM: 256 blocks x 256 threads -- FULL GPU (v1-v6 used 64 CUs, 192 idle).
// Block (b,k) owns units [64k,64k+64): 256 gate-columns, weight slice 128 KB
// = 128 VGPRs/thread -> register-resident with slack (~190 arch total, no
// remat pressure). h exchanged per step via L2 global buffer + per-block
// monotonic flags (agent-scope acquire/release). In-block h broadcast via
// readlane->SGPR feeding v_dot2 (v2-proven path) -> no LDS wall, no AGPRs.
// 96 KB dummy dynamic LDS forces 1 block/CU => grid 256 == capacity => all
// blocks co-resident (flag sync safe without cooperative launch).

typedef _Float16 h2_t __attribute__((ext_vector_type(2)));
typedef unsigned u32x4 __attribute__((ext_vector_type(4)));
typedef float    f32x4 __attribute__((ext_vector_type(4)));

#if defined(__has_builtin)
#if __has_builtin(__builtin_amdgcn_fdot2)
#define HAVE_FDOT2 1
#endif
#endif

__device__ __forceinline__ float fdot2(unsigned w, unsigned h, float acc) {
#ifdef HAVE_FDOT2
    return __builtin_amdgcn_fdot2(__builtin_bit_cast(h2_t, w),
                                  __builtin_bit_cast(h2_t, h), acc, false);
#else
    h2_t wv = __builtin_bit_cast(h2_t, w), hv = __builtin_bit_cast(h2_t, h);
    return acc + (float)wv.x * (float)hv.x + (float)wv.y * (float)hv.y;
#endif
}

__device__ __forceinline__ unsigned pack2(float a, float b) {
    unsigned la = (unsigned)__builtin_bit_cast(unsigned short, (_Float16)a);
    unsigned lb = (unsigned)__builtin_bit_cast(unsigned short, (_Float16)b);
    return la | (lb << 16);
}

// ---------------------------------------------------------------------------
// Pack w_hh -> whhP[k][g][q][u] uint4 (q = K-chunk 0..31, u = unit-in-slice).
// Thread (g,u) of block k loads wp[q*64] -> per-wave coalesced (g uniform,
// u = lane). Also wihT[k][1024] fp32 for x_gemm. grid 1024 (col), 128 thr.
// ---------------------------------------------------------------------------
__global__ void pack_weights(const float* __restrict__ w_ih,
                             const float* __restrict__ w_hh,
                             unsigned* __restrict__ whhP,   // [4][4][32][64] uint4, flat dwords
                             float* __restrict__ wihT) {    // [64][1024]
    int col = blockIdx.x, d = threadIdx.x;   // d = packed dword 0..127
    int g = col >> 8, m8 = col & 255;
    int k = m8 >> 6, u = m8 & 63;
    const float* wr = w_hh + col * HID;
    unsigned p = pack2(wr[2 * d], wr[2 * d + 1]);
    int q = d >> 2, e = d & 3;
    whhP[((((k * 4 + g) * 32 + q) * 64 + u)) * 4 + e] = p;
    if (d < COUT) wihT[d * 1024 + col] = w_ih[col * COUT + d];
}

// conv weight permute: wc2[j][oc], j = kk*128+ic
__global__ void prep_conv_w(const float* __restrict__ conv_w, float* __restrict__ wc2) {
    int i = blockIdx.x * 256 + threadIdx.x;
    if (i < 24576) {
        int j = i >> 6, oc = i & 63;
        int kk = j >> 7, ic = j & 127;
        wc2[i] = conv_w[(oc * 128 + ic) * 3 + kk];
    }
}

// ---------------------------------------------------------------------------
// partial sum-of-squares over time (F.normalize along dim=1)
// ---------------------------------------------------------------------------
__global__ void norm_partial(const float* __restrict__ in, float* __restrict__ part) {
    int b = blockIdx.x, ch = blockIdx.y, f = threadIdx.x;
    const float* p = in + ((size_t)b * T_N + (size_t)ch * CHUNK_T) * FIN + f;
    float s0 = 0.f, s1 = 0.f, s2 = 0.f, s3 = 0.f;
#pragma unroll
    for (int r = 0; r < CHUNK_T; r += 4) {
        float v0 = p[(r + 0) * FIN];
        float v1 = p[(r + 1) * FIN];
        float v2 = p[(r + 2) * FIN];
        float v3 = p[(r + 3) * FIN];
        s0 += v0 * v0; s1 += v1 * v1; s2 += v2 * v2; s3 += v3 * v3;
    }
    part[(b * NCHUNK + ch) * FIN + f] = (s0 + s1) + (s2 + s3);
}

// ---------------------------------------------------------------------------
// normalize + conv1d(k=3,stride=3) + bias + relu  (stride==K -> GEMM)
// ---------------------------------------------------------------------------
__global__ __launch_bounds__(256) void conv_relu(
        const float* __restrict__ in, const float* __restrict__ part,
        const float* __restrict__ wc2, const float* __restrict__ cb,
        float* __restrict__ X) {
    __shared__ __align__(16) float xs[16 * 384];
    __shared__ __align__(16) float wsh[96 * 64];
    __shared__ float invn[FIN];

    int b = blockIdx.x, tile = blockIdx.y;
    int tid = threadIdx.x;

    if (tid < FIN) {
        float s = 0.f;
#pragma unroll
        for (int c = 0; c < NCHUNK; c++) s += part[(b * NCHUNK + c) * FIN + tid];
        invn[tid] = rsqrtf(fmaxf(s, 1e-24f));
    }
    __syncthreads();

    const float* ip = in + ((size_t)b * T_N + (size_t)tile * 48) * FIN;
    for (int i = tid; i < 6144; i += 256) xs[i] = ip[i] * invn[i & 127];

    int oc = tid & 63, tq = tid >> 6;
    float acc0 = 0.f, acc1 = 0.f, acc2 = 0.f, acc3 = 0.f;
    const float* xb = xs + tq * 4 * 384;

    for (int c = 0; c < 4; c++) {
        __syncthreads();
        for (int i = tid; i < 6144; i += 256) wsh[i] = wc2[c * 6144 + i];
        __syncthreads();
#pragma unroll 8
        for (int jj = 0; jj < 96; jj += 4) {
            int j = c * 96 + jj;
            float w0 = wsh[(jj + 0) * 64 + oc];
            float w1 = wsh[(jj + 1) * 64 + oc];
            float w2 = wsh[(jj + 2) * 64 + oc];
            float w3 = wsh[(jj + 3) * 64 + oc];
            float4 x0 = *(const float4*)(xb + j);
            float4 x1 = *(const float4*)(xb + 384 + j);
            float4 x2 = *(const float4*)(xb + 768 + j);
            float4 x3 = *(const float4*)(xb + 1152 + j);
            acc0 += w0 * x0.x + w1 * x0.y + w2 * x0.z + w3 * x0.w;
            acc1 += w0 * x1.x + w1 * x1.y + w2 * x1.z + w3 * x1.w;
            acc2 += w0 * x2.x + w1 * x2.y + w2 * x2.z + w3 * x2.w;
            acc3 += w0 * x3.x + w1 * x3.y + w2 * x3.z + w3 * x3.w;
        }
    }
    float bb = cb[oc];
    int tp0 = tile * 16 + tq * 4;
    size_t o = ((size_t)b * TP + tp0) * COUT + oc;
    X[o]       = fmaxf(acc0 + bb, 0.f);
    X[o + 64]  = fmaxf(acc1 + bb, 0.f);
    X[o + 128] = fmaxf(acc2 + bb, 0.f);
    X[o + 192] = fmaxf(acc3 + bb, 0.f);
}

// ---------------------------------------------------------------------------
// x-projection GEMM: xg[b][t][c] = X[b,t,:] @ w_ih[c,:] + b_ih[c] + b_hh[c],
// stored f16 in NATURAL column order. grid (64 b, 64 t-tiles of 16), 256 thr.
// ---------------------------------------------------------------------------
__global__ __launch_bounds__(256) void x_gemm(
        const float* __restrict__ X, const float* __restrict__ wihT,
        const float* __restrict__ b_ih, const float* __restrict__ b_hh,
        _Float16* __restrict__ xg) {
    __shared__ __align__(16) float xs[64 * 20];   // [k][r], row stride 20
    int b = blockIdx.x, t0 = blockIdx.y * 16, tid = threadIdx.x;

    const float* Xp = X + ((size_t)b * TP + t0) * COUT;
    for (int i = tid; i < 1024; i += 256) {
        int r = i >> 6, k = i & 63;
        xs[k * 20 + r] = Xp[i];
    }
    __syncthreads();

    int cI = tid, cF = tid + 256, cG = tid + 512, cO = tid + 768;
    float bI = b_ih[cI] + b_hh[cI];
    float bF = b_ih[cF] + b_hh[cF];
    float bG = b_ih[cG] + b_hh[cG];
    float bO = b_ih[cO] + b_hh[cO];

    f32x4 aI[4], aF[4], aG[4], aO[4];
#pragma unroll
    for (int q = 0; q < 4; q++) {
        aI[q] = bI; aF[q] = bF; aG[q] = bG; aO[q] = bO;
    }

    for (int k = 0; k < 64; k++) {
        float wI = wihT[k * 1024 + cI];
        float wF = wihT[k * 1024 + cF];
        float wG = wihT[k * 1024 + cG];
        float wO = wihT[k * 1024 + cO];
        const f32x4* xv = (const f32x4*)(xs + k * 20);
#pragma unroll
        for (int q = 0; q < 4; q++) {
            f32x4 x4 = xv[q];
            aI[q] += wI * x4;
            aF[q] += wF * x4;
            aG[q] += wG * x4;
            aO[q] += wO * x4;
        }
    }

    _Float16* xh = xg + ((size_t)b * TP + t0) * 1024;
#pragma unroll
    for (int r = 0; r < 16; r++) {
        int q = r >> 2, e = r & 3;
        size_t ro = (size_t)r * 1024;
        xh[ro + cI] = (_Float16)aI[q][e];
        xh[ro + cF] = (_Float16)aF[q][e];
        xh[ro + cG] = (_Float16)aG[q][e];
        xh[ro + cO] = (_Float16)aO[q][e];
    }
}

// ---------------------------------------------------------------------------
// init: h(0) f16x2 into hbuf parity 0; zero flags. Runs AFTER conv_relu
// (hbuf/flags reuse the 'part' workspace region). grid 64, 128 thr.
// ---------------------------------------------------------------------------
__global__ void init_sync(const float* __restrict__ hx0,
                          unsigned* __restrict__ hbufU,
                          unsigned* __restrict__ flags) {
    int b = blockIdx.x, d = threadIdx.x;
    const float* h = hx0 + b * HID;
    hbufU[(size_t)b * 128 + d] = pack2(h[2 * d], h[2 * d + 1]);
    if (d < NBLK) flags[b * NBLK + d] = 0;
}

// ---------------------------------------------------------------------------
// Persistent LSTM v7 (split recurrence)
// ---------------------------------------------------------------------------
__device__ __forceinline__ float fsig(float x) {
    return 1.f / (1.f + __expf(-x));
}
__device__ __forceinline__ float ftanh(float x) {
    float xc = fminf(fmaxf(x, -15.f), 15.f);
    float e = __expf(2.f * xc);
    return (e - 1.f) / (e + 1.f);
}

#define SM_SIZE 98304   // dummy-large: forces 1 block/CU (LDS pool 160 KB)

#define REPW(M) M(0) M(1) M(2) M(3) M(4) M(5) M(6) M(7) M(8) M(9) M(10) M(11) \
                M(12) M(13) M(14) M(15) M(16) M(17) M(18) M(19) M(20) M(21) \
                M(22) M(23) M(24) M(25) M(26) M(27) M(28) M(29) M(30) M(31)

#define DLW(q)  u32x4 w##q = wp[(q) * 64];

// chunk q covers h dwords 4q..4q+3: lane 2q holds (4q,4q+1), lane 2q+1 the rest
#define DOTQ(q, A) { \
    unsigned h0 = (unsigned)__builtin_amdgcn_readlane((int)hvv.x, 2 * (q)); \
    unsigned h1 = (unsigned)__builtin_amdgcn_readlane((int)hvv.y, 2 * (q)); \
    unsigned h2 = (unsigned)__builtin_amdgcn_readlane((int)hvv.x, 2 * (q) + 1); \
    unsigned h3 = (unsigned)__builtin_amdgcn_readlane((int)hvv.y, 2 * (q) + 1); \
    A = fdot2(w##q[0], h0, A); A = fdot2(w##q[1], h1, A); \
    A = fdot2(w##q[2], h2, A); A = fdot2(w##q[3], h3, A); }

#define DOTS8(q0,q1,q2,q3,q4,q5,q6,q7) \
    DOTQ(q0, a0) DOTQ(q1, a1) DOTQ(q2, a2) DOTQ(q3, a3) \
    DOTQ(q4, a0) DOTQ(q5, a1) DOTQ(q6, a2) DOTQ(q7, a3)

__global__ __attribute__((amdgpu_flat_work_group_size(256, 256)))
void lstm_kernel(
        const u32x4* __restrict__ whhP4,
        const _Float16* __restrict__ xg,
        const float* __restrict__ cx0,
        unsigned* __restrict__ hbufU,
        unsigned* __restrict__ flags,
        float* __restrict__ hfin) {
    extern __shared__ float acts[];   // [4][64] used; rest is occupancy ballast

    // (b,k) mapping keeps a batch's 4 blocks on one XCD under blk%8 dispatch
    // (speed heuristic only; correctness is agent-scope either way).
    const int blk = blockIdx.x;
    const int slot = blk >> 3;
    const int b = (blk & 7) + 8 * (slot & 7);
    const int k = slot >> 3;
    const int tid = threadIdx.x;
    const int g = tid >> 6, u = tid & 63;   // gate = wave, unit-in-slice = lane

    // 128 register-resident weight dwords (32 x u32x4 named SSA)
    const u32x4* wp = whhP4 + ((size_t)(k * 4 + g) * 32) * 64 + u;
    REPW(DLW)

    const _Float16* xcol = xg + (size_t)b * TP * G4 + (g * 256 + k * 64 + u);
    _Float16 xcur = xcol[0];

    float c_reg = (tid < 64) ? cx0[b * HID + k * 64 + tid] : 0.f;
    _Float16* hbH = (_Float16*)hbufU;

    for (int t = 0; t < TP; t++) {
        // prefetch next x-projection (hidden under this step)
        int tn = (t + 1 < TP) ? t + 1 : t;
        _Float16 xnxt = xcol[(size_t)tn * G4];

        // wait for h(t): flag[b][*] >= t  (monotonic; no ABA, no reset races).
        // flag==t implies every block finished READING h(t-1) (reads precede
        // the tail that sets the flag), so parity reuse below is race-free.
        if (u < NBLK) {
            unsigned want = (unsigned)t;
            int guard = 0;
            while (__hip_atomic_load(&flags[b * NBLK + u], __ATOMIC_ACQUIRE,
                                     __HIP_MEMORY_SCOPE_AGENT) < want) {
                if (++guard > (1 << 22)) break;   // bail-out: no harness hang
            }
        }
        __builtin_amdgcn_fence(__ATOMIC_ACQUIRE, "agent");

        // gather h(t): lane l -> dwords 2l,2l+1 (512 B, L2-hot)
        const uint2* hp = (const uint2*)(hbufU + ((size_t)(t & 1) * 64 + b) * 128);
        uint2 hvv = hp[u];

        float a0 = 0.f, a1 = 0.f, a2 = 0.f, a3 = 0.f;
        DOTS8(0, 1, 2, 3, 4, 5, 6, 7)
        DOTS8(8, 9, 10, 11, 12, 13, 14, 15)
        DOTS8(16, 17, 18, 19, 20, 21, 22, 23)
        DOTS8(24, 25, 26, 27, 28, 29, 30, 31)

        float a = (float)xcur + ((a0 + a1) + (a2 + a3));   // bias folded in xg
        float act = (g == 2) ? ftanh(a) : fsig(a);         // g-gate tanh, else sig
        acts[g * 64 + u] = act;
        __syncthreads();

        if (tid < 64) {   // wave 0: cell update for its 64 units
            float i_ = acts[tid];
            float f_ = acts[64 + tid];
            float g_ = acts[128 + tid];
            float o_ = acts[192 + tid];
            c_reg = f_ * c_reg + i_ * g_;
            float hh = o_ * ftanh(c_reg);
            if (t + 1 < TP) {
                hbH[((size_t)((t + 1) & 1) * 64 + b) * 256 + k * 64 + tid] =
                    (_Float16)hh;
                __threadfence();   // agent release: stores + acts reads done
                if (tid == 0)
                    __hip_atomic_store(&flags[b * NBLK + k], (unsigned)(t + 1),
                                       __ATOMIC_RELEASE, __HIP_MEMORY_SCOPE_AGENT);
            } else {
                hfin[b * HID + k * 64 + tid] = hh;
            }
        }
        xcur = xnxt;
    }
}

// ---------------------------------------------------------------------------
// final linear: out[b] = hfin[b] @ lin_w.T + lin_b. grid 64, 64 thr.
// ---------------------------------------------------------------------------
__global__ void out_lin(const float* __restrict__ hfin,
                        const float* __restrict__ lin_w,
                        const float* __restrict__ lin_b,
                        float* __restrict__ out) {
    int b = blockIdx.x, j = threadIdx.x;
    if (j < OUT_N) {
        float s = lin_b[j];
        const float* lw = lin_w + j * HID;
        const float* hf = hfin + b * HID;
#pragma unroll 4
        for (int n = 0; n < HID; n++) s += hf[n] * lw[n];
        out[b * OUT_N + j] = s;
    }
}

// ---------------------------------------------------------------------------
extern "C" void kernel_launch(void* const* d_in, const int* in_sizes, int n_in,
                              void* d_out, int out_size, void* d_ws, size_t ws_size,
                              hipStream_t stream) {
    const float* input  = (const float*)d_in[0];
    // d_in[1] = r (unused)
    const float* hx0    = (const float*)d_in[2];
    const float* cx0    = (const float*)d_in[3];
    const float* conv_w = (const float*)d_in[4];
    const float* conv_b = (const float*)d_in[5];
    const float* w_ih   = (const float*)d_in[6];
    const float* b_ih   = (const float*)d_in[7];
    const float* w_hh   = (const float*)d_in[8];
    const float* b_hh   = (const float*)d_in[9];
    const float* lin_w  = (const float*)d_in[10];
    const float* lin_b  = (const float*)d_in[11];

    float* ws = (float*)d_ws;
    float*     part = ws;                      // 196608 floats (reused below)
    float*     X    = part + 196608;           // 4194304 floats
    float*     wc2  = X + 4194304;             // 24576 floats
    float*     wihT = wc2 + 24576;             // 65536 floats
    unsigned*  whhP = (unsigned*)(wihT + 65536);        // 131072 dwords (512 KB)
    _Float16*  xg   = (_Float16*)(whhP + 131072);       // 64*1024*1024 halves

    // sync state reuses 'part' (free after conv_relu; init_sync runs after)
    unsigned*  hbufU = (unsigned*)part;        // [2][64][128] dwords (f16x2 h)
    unsigned*  flags = hbufU + 2 * 64 * 128;   // [64][4]
    float*     hfin  = (float*)(flags + 256);  // [64][256]

    (void)hipFuncSetAttribute((const void*)lstm_kernel,
                              hipFuncAttributeMaxDynamicSharedMemorySize, SM_SIZE);

    pack_weights<<<1024, 128, 0, stream>>>(w_ih, w_hh, whhP, wihT);
    prep_conv_w<<<96, 256, 0, stream>>>(conv_w, wc2);
    norm_partial<<<dim3(B_N, NCHUNK), FIN, 0, stream>>>(input, part);
    conv_relu<<<dim3(B_N, 64), 256, 0, stream>>>(input, part, wc2, conv_b, X);
    init_sync<<<B_N, 128, 0, stream>>>(hx0, hbufU, flags);
    x_gemm<<<dim3(B_N, 64), 256, 0, stream>>>(X, wihT, b_ih, b_hh, xg);
    lstm_kernel<<<B_N * NBLK, 256, SM_SIZE, stream>>>(
        (const u32x4*)whhP, xg, cx0, hbufU, flags, hfin);
    out_lin<<<B_N, 64, 0, stream>>>(hfin, lin_w, lin_b, (float*)d_out);
}

// Round 8
// 3325.750 us; speedup vs baseline: 10.4130x; 10.4130x over previous
//
#include <hip/hip_runtime.h>
#include <math.h>

#define B_N 64
#define T_N 3072
#define FIN 128
#define TP 1024      // conv output length
#define COUT 64
#define HID 256
#define G4 1024      // 4*HID
#define OUT_N 10
#define NCHUNK 24
#define CHUNK_T (T_N / NCHUNK)   // 128

// v8 = round-0 (v1, 2055us lstm) structure EXACTLY, plus a minimal safe pin:
//   12 chunks VGPR-pinned via ONE asm launder (96 VGPRs; 96+116 arch = 212
//     <= 256 budget -> no spill; asm-defined values cannot be remat'd)
//   12 chunks streamed from L2 per step (196 KB/CU/step, half of v1's 393KB;
//     two 6-chunk clumps, pointer-laundered against loop-invariant hoisting)
//    8 chunks LDS (128 KB) -- unchanged from v1
// v1..v7 lessons: per-use volatile asm serializes (v6), AGPR overflow spills
// (v3/v4), 1 wave/EU exposes latency (v5), cross-block sync costs us/step (v7).
#define WREG 12
#define WSTR 12
#define WLDS 8

typedef _Float16 h2_t __attribute__((ext_vector_type(2)));
typedef unsigned u32x4 __attribute__((ext_vector_type(4)));

#if defined(__has_builtin)
#if __has_builtin(__builtin_amdgcn_fdot2)
#define HAVE_FDOT2 1
#endif
#endif

__device__ __forceinline__ float fdot2(unsigned w, unsigned h, float acc) {
#ifdef HAVE_FDOT2
    return __builtin_amdgcn_fdot2(__builtin_bit_cast(h2_t, w),
                                  __builtin_bit_cast(h2_t, h), acc, false);
#else
    h2_t wv = __builtin_bit_cast(h2_t, w), hv = __builtin_bit_cast(h2_t, h);
    return acc + (float)wv.x * (float)hv.x + (float)wv.y * (float)hv.y;
#endif
}

__device__ __forceinline__ unsigned pack2(float a, float b) {
    unsigned la = (unsigned)__builtin_bit_cast(unsigned short, (_Float16)a);
    unsigned lb = (unsigned)__builtin_bit_cast(unsigned short, (_Float16)b);
    return la | (lb << 16);
}

// ---------------------------------------------------------------------------
// Pack w_hh to f16x2 chunk layout [chunk c][col] (uint4 granules), split
// R(0..11)/S(12..23)/L(24..31), and build wihT[k][1024] fp32 for x_gemm.
// grid 1024 (col), 128 thr (d).
// ---------------------------------------------------------------------------
__global__ void pack_weights(const float* __restrict__ w_ih,
                             const float* __restrict__ w_hh,
                             unsigned* __restrict__ whhR,   // [12][1024] uint4, flat dwords
                             unsigned* __restrict__ whhS,   // [12][1024]
                             unsigned* __restrict__ whhL,   // [8][1024]
                             float* __restrict__ wihT) {    // [64][1024]
    int col = blockIdx.x, d = threadIdx.x;   // d = packed dword 0..127
    const float* wr = w_hh + col * HID;
    unsigned p = pack2(wr[2 * d], wr[2 * d + 1]);
    int c = d >> 2, r = d & 3;
    if (c < WREG)             whhR[(c * 1024 + col) * 4 + r] = p;
    else if (c < WREG + WSTR) whhS[((c - WREG) * 1024 + col) * 4 + r] = p;
    else                      whhL[((c - WREG - WSTR) * 1024 + col) * 4 + r] = p;
    if (d < COUT) wihT[d * 1024 + col] = w_ih[col * COUT + d];
}

// conv weight permute: wc2[j][oc], j = kk*128+ic
__global__ void prep_conv_w(const float* __restrict__ conv_w, float* __restrict__ wc2) {
    int i = blockIdx.x * 256 + threadIdx.x;
    if (i < 24576) {
        int j = i >> 6, oc = i & 63;
        int kk = j >> 7, ic = j & 127;
        wc2[i] = conv_w[(oc * 128 + ic) * 3 + kk];
    }
}

// ---------------------------------------------------------------------------
// partial sum-of-squares over time (F.normalize along dim=1)
// ---------------------------------------------------------------------------
__global__ void norm_partial(const float* __restrict__ in, float* __restrict__ part) {
    int b = blockIdx.x, ch = blockIdx.y, f = threadIdx.x;
    const float* p = in + ((size_t)b * T_N + (size_t)ch * CHUNK_T) * FIN + f;
    float s0 = 0.f, s1 = 0.f, s2 = 0.f, s3 = 0.f;
#pragma unroll
    for (int r = 0; r < CHUNK_T; r += 4) {
        float v0 = p[(r + 0) * FIN];
        float v1 = p[(r + 1) * FIN];
        float v2 = p[(r + 2) * FIN];
        float v3 = p[(r + 3) * FIN];
        s0 += v0 * v0; s1 += v1 * v1; s2 += v2 * v2; s3 += v3 * v3;
    }
    part[(b * NCHUNK + ch) * FIN + f] = (s0 + s1) + (s2 + s3);
}

// ---------------------------------------------------------------------------
// normalize + conv1d(k=3,stride=3) + bias + relu  (stride==K -> GEMM)
// ---------------------------------------------------------------------------
__global__ __launch_bounds__(256) void conv_relu(
        const float* __restrict__ in, const float* __restrict__ part,
        const float* __restrict__ wc2, const float* __restrict__ cb,
        float* __restrict__ X) {
    __shared__ __align__(16) float xs[16 * 384];
    __shared__ __align__(16) float wsh[96 * 64];
    __shared__ float invn[FIN];

    int b = blockIdx.x, tile = blockIdx.y;
    int tid = threadIdx.x;

    if (tid < FIN) {
        float s = 0.f;
#pragma unroll
        for (int c = 0; c < NCHUNK; c++) s += part[(b * NCHUNK + c) * FIN + tid];
        invn[tid] = rsqrtf(fmaxf(s, 1e-24f));
    }
    __syncthreads();

    const float* ip = in + ((size_t)b * T_N + (size_t)tile * 48) * FIN;
    for (int i = tid; i < 6144; i += 256) xs[i] = ip[i] * invn[i & 127];

    int oc = tid & 63, tq = tid >> 6;
    float acc0 = 0.f, acc1 = 0.f, acc2 = 0.f, acc3 = 0.f;
    const float* xb = xs + tq * 4 * 384;

    for (int c = 0; c < 4; c++) {
        __syncthreads();
        for (int i = tid; i < 6144; i += 256) wsh[i] = wc2[c * 6144 + i];
        __syncthreads();
#pragma unroll 8
        for (int jj = 0; jj < 96; jj += 4) {
            int j = c * 96 + jj;
            float w0 = wsh[(jj + 0) * 64 + oc];
            float w1 = wsh[(jj + 1) * 64 + oc];
            float w2 = wsh[(jj + 2) * 64 + oc];
            float w3 = wsh[(jj + 3) * 64 + oc];
            float4 x0 = *(const float4*)(xb + j);
            float4 x1 = *(const float4*)(xb + 384 + j);
            float4 x2 = *(const float4*)(xb + 768 + j);
            float4 x3 = *(const float4*)(xb + 1152 + j);
            acc0 += w0 * x0.x + w1 * x0.y + w2 * x0.z + w3 * x0.w;
            acc1 += w0 * x1.x + w1 * x1.y + w2 * x1.z + w3 * x1.w;
            acc2 += w0 * x2.x + w1 * x2.y + w2 * x2.z + w3 * x2.w;
            acc3 += w0 * x3.x + w1 * x3.y + w2 * x3.z + w3 * x3.w;
        }
    }
    float bb = cb[oc];
    int tp0 = tile * 16 + tq * 4;
    size_t o = ((size_t)b * TP + tp0) * COUT + oc;
    X[o]       = fmaxf(acc0 + bb, 0.f);
    X[o + 64]  = fmaxf(acc1 + bb, 0.f);
    X[o + 128] = fmaxf(acc2 + bb, 0.f);
    X[o + 192] = fmaxf(acc3 + bb, 0.f);
}

// ---------------------------------------------------------------------------
// x-projection GEMM: xg[b,t,j] = X[b,t,:] @ w_ih[j,:] + b_ih[j] + b_hh[j],
// stored f16. grid (64 b, 64 t-tiles of 16), 256 threads.   (round-0 version)
// ---------------------------------------------------------------------------
__global__ __launch_bounds__(256) void x_gemm(
        const float* __restrict__ X, const float* __restrict__ wihT,
        const float* __restrict__ b_ih, const float* __restrict__ b_hh,
        _Float16* __restrict__ xg) {
    __shared__ float xs[64 * 17];   // [k][r], padded
    int b = blockIdx.x, t0 = blockIdx.y * 16, tid = threadIdx.x;

    const float* Xp = X + ((size_t)b * TP + t0) * COUT;
    for (int i = tid; i < 1024; i += 256) {
        int r = i >> 6, k = i & 63;
        xs[k * 17 + r] = Xp[i];
    }
    __syncthreads();

#pragma unroll
    for (int jt = 0; jt < 4; jt++) {
        int jj = jt * 256 + tid;
        float bias = b_ih[jj] + b_hh[jj];
        float acc[16];
#pragma unroll
        for (int r = 0; r < 16; r++) acc[r] = bias;
        for (int k = 0; k < 64; k++) {
            float w = wihT[k * 1024 + jj];
#pragma unroll
            for (int r = 0; r < 16; r++) acc[r] += w * xs[k * 17 + r];
        }
#pragma unroll
        for (int r = 0; r < 16; r++)
            xg[((size_t)b * TP + t0 + r) * 1024 + jj] = (_Float16)acc[r];
    }
}

// ---------------------------------------------------------------------------
// Persistent LSTM v8: round-0 structure (512 thr, 2 waves/EU, LDS h-broadcast,
// fo_s exchange, 2 barriers) + 12-chunk asm-laundered VGPR pin + 12-chunk
// explicit 2-clump stream + 8-chunk LDS.
// ---------------------------------------------------------------------------
__device__ __forceinline__ float fsig(float x) {
    return 1.f / (1.f + __expf(-x));
}
__device__ __forceinline__ float ftanh(float x) {
    float xc = fminf(fmaxf(x, -15.f), 15.f);
    float e = __expf(2.f * xc);
    return (e - 1.f) / (e + 1.f);
}

#define SM_WL   0
#define SM_H    131072
#define SM_FO   131584
#define SM_H32  133632
#define SM_SIZE 134656

#define REP12(M) M(0) M(1) M(2) M(3) M(4) M(5) M(6) M(7) M(8) M(9) M(10) M(11)
#define REP8(M)  M(0) M(1) M(2) M(3) M(4) M(5) M(6) M(7)

#define DECLW(n)  u32x4 wa##n, wb##n;
#define LOADW(n)  wa##n = whhR4[(n) * 1024 + j]; wb##n = whhR4[(n) * 1024 + j + 512];

// pinned chunk n covers h chunk n
#define DOTCH(n)  { u32x4 H = hs4[n]; \
    a0 = fdot2(wa##n[0], H[0], a0); a1 = fdot2(wb##n[0], H[0], a1); \
    a0 = fdot2(wa##n[1], H[1], a0); a1 = fdot2(wb##n[1], H[1], a1); \
    a0 = fdot2(wa##n[2], H[2], a0); a1 = fdot2(wb##n[2], H[2], a1); \
    a0 = fdot2(wa##n[3], H[3], a0); a1 = fdot2(wb##n[3], H[3], a1); }

// streamed chunk q covers h chunk 12+q
#define SDECL(q)  u32x4 sa##q, sb##q;
#define SLOADQ(q) sa##q = sp[(q) * 1024 + j]; sb##q = sp[(q) * 1024 + j + 512];
#define DOTSTR(q) { u32x4 H = hs4[WREG + (q)]; \
    a0 = fdot2(sa##q[0], H[0], a0); a1 = fdot2(sb##q[0], H[0], a1); \
    a0 = fdot2(sa##q[1], H[1], a0); a1 = fdot2(sb##q[1], H[1], a1); \
    a0 = fdot2(sa##q[2], H[2], a0); a1 = fdot2(sb##q[2], H[2], a1); \
    a0 = fdot2(sa##q[3], H[3], a0); a1 = fdot2(sb##q[3], H[3], a1); }

// LDS chunk m covers h chunk 24+m
#define DOTLDS(m) { u32x4 WA = wL[(m) * 1024 + j]; u32x4 WB = wL[(m) * 1024 + j + 512]; \
    u32x4 H = hs4[WREG + WSTR + (m)]; \
    a0 = fdot2(WA[0], H[0], a0); a1 = fdot2(WB[0], H[0], a1); \
    a0 = fdot2(WA[1], H[1], a0); a1 = fdot2(WB[1], H[1], a1); \
    a0 = fdot2(WA[2], H[2], a0); a1 = fdot2(WB[2], H[2], a1); \
    a0 = fdot2(WA[3], H[3], a0); a1 = fdot2(WB[3], H[3], a1); }

__global__ __attribute__((amdgpu_flat_work_group_size(512, 512),
                          amdgpu_waves_per_eu(2, 2)))
void lstm_kernel(
        const u32x4* __restrict__ whhR4, const u32x4* __restrict__ whhS4,
        const u32x4* __restrict__ whhL4,
        const _Float16* __restrict__ xg,
        const float* __restrict__ hx0, const float* __restrict__ cx0,
        const float* __restrict__ lin_w, const float* __restrict__ lin_b,
        float* __restrict__ out) {
    extern __shared__ char smem[];
    u32x4*    wL    = (u32x4*)(smem + SM_WL);       // [8][1024] uint4
    _Float16* h_s   = (_Float16*)(smem + SM_H);     // 256
    float2*   fo_s  = (float2*)(smem + SM_FO);      // 256
    float*    h32_s = (float*)(smem + SM_H32);      // 256

    const int b = blockIdx.x, j = threadIdx.x;

    // 12 chunks loaded once, then laundered through ONE asm: values become
    // asm-defined -> cannot be remat'd back into the loop. 96 VGPRs.
    REP12(DECLW)
    REP12(LOADW)
    asm volatile("" :
        "+v"(wa0), "+v"(wb0), "+v"(wa1), "+v"(wb1),
        "+v"(wa2), "+v"(wb2), "+v"(wa3), "+v"(wb3),
        "+v"(wa4), "+v"(wb4), "+v"(wa5), "+v"(wb5),
        "+v"(wa6), "+v"(wb6), "+v"(wa7), "+v"(wb7),
        "+v"(wa8), "+v"(wb8), "+v"(wa9), "+v"(wb9),
        "+v"(wa10), "+v"(wb10), "+v"(wa11), "+v"(wb11));

    // stage LDS-resident chunks
    for (int i = j; i < WLDS * 1024; i += 512) wL[i] = whhL4[i];

    float c_reg = 0.f;
    if (j < HID) {
        c_reg = cx0[b * HID + j];
        h_s[j] = (_Float16)hx0[b * HID + j];
    }
    const _Float16* Xg = xg + (size_t)b * TP * G4;
    _Float16 xa = Xg[j], xb = Xg[j + 512];
    __syncthreads();

    const u32x4* hs4 = (const u32x4*)h_s;   // 32 chunks of 8 h-values

    for (int t = 0; t < TP; t++) {
        // stream pointer laundered per-iteration: loads are loop-variant ->
        // cannot be hoisted into (spilled) residency.
        const u32x4* sp = whhS4;
        asm volatile("" : "+v"(sp));

        SDECL(0) SDECL(1) SDECL(2) SDECL(3) SDECL(4) SDECL(5)
        SDECL(6) SDECL(7) SDECL(8) SDECL(9) SDECL(10) SDECL(11)
        // clump 1: issue 6 chunks; latency hides under pinned-chunk dots
        SLOADQ(0) SLOADQ(1) SLOADQ(2) SLOADQ(3) SLOADQ(4) SLOADQ(5)

        _Float16 xan = (_Float16)0.f, xbn = (_Float16)0.f;
        if (t + 1 < TP) {
            xan = Xg[(t + 1) * G4 + j];
            xbn = Xg[(t + 1) * G4 + j + 512];
        }

        float a0 = (float)xa, a1 = (float)xb;   // bias folded into xg
        DOTCH(0) DOTCH(1) DOTCH(2) DOTCH(3) DOTCH(4) DOTCH(5)
        DOTCH(6) DOTCH(7) DOTCH(8) DOTCH(9) DOTCH(10) DOTCH(11)

        // clump 2 issued before clump-1 consumption
        SLOADQ(6) SLOADQ(7) SLOADQ(8) SLOADQ(9) SLOADQ(10) SLOADQ(11)

        DOTSTR(0) DOTSTR(1) DOTSTR(2) DOTSTR(3) DOTSTR(4) DOTSTR(5)
        DOTLDS(0) DOTLDS(1) DOTLDS(2) DOTLDS(3)
        DOTLDS(4) DOTLDS(5) DOTLDS(6) DOTLDS(7)
        DOTSTR(6) DOTSTR(7) DOTSTR(8) DOTSTR(9) DOTSTR(10) DOTSTR(11)

        float s0 = 0.f, s1 = 0.f;
        if (j >= HID) {
            fo_s[j - HID] = make_float2(fsig(a0), fsig(a1));   // sig(f), sig(o)
        } else {
            s0 = fsig(a0);    // sig(i)
            s1 = ftanh(a1);   // tanh(g)
        }
        __syncthreads();
        if (j < HID) {
            float2 fo = fo_s[j];
            c_reg = fo.x * c_reg + s0 * s1;
            float hh = fo.y * ftanh(c_reg);
            h_s[j] = (_Float16)hh;
            if (t == TP - 1) h32_s[j] = hh;
        }
        __syncthreads();
        xa = xan; xb = xbn;
    }

    // epilogue: out[b] = h @ lin_w.T + lin_b  (fp32 h)
    if (j < OUT_N) {
        float s = lin_b[j];
        const float* lw = lin_w + j * HID;
#pragma unroll 4
        for (int k = 0; k < HID; k++) s += h32_s[k] * lw[k];
        out[b * OUT_N + j] = s;
    }
}

// ---------------------------------------------------------------------------
extern "C" void kernel_launch(void* const* d_in, const int* in_sizes, int n_in,
                              void* d_out, int out_size, void* d_ws, size_t ws_size,
                              hipStream_t stream) {
    const float* input  = (const float*)d_in[0];
    // d_in[1] = r (unused)
    const float* hx0    = (const float*)d_in[2];
    const float* cx0    = (const float*)d_in[3];
    const float* conv_w = (const float*)d_in[4];
    const float* conv_b = (const float*)d_in[5];
    const float* w_ih   = (const float*)d_in[6];
    const float* b_ih   = (const float*)d_in[7];
    const float* w_hh   = (const float*)d_in[8];
    const float* b_hh   = (const float*)d_in[9];
    const float* lin_w  = (const float*)d_in[10];
    const float* lin_b  = (const float*)d_in[11];

    float* ws = (float*)d_ws;
    float*     part = ws;                      // 196608 floats
    float*     X    = part + 196608;           // 4194304 floats
    float*     wc2  = X + 4194304;             // 24576 floats
    float*     wihT = wc2 + 24576;             // 65536 floats
    unsigned*  whhR = (unsigned*)(wihT + 65536);    // 12*1024*4 dwords
    unsigned*  whhS = whhR + WREG * 1024 * 4;       // 12*1024*4 dwords
    unsigned*  whhL = whhS + WSTR * 1024 * 4;       // 8*1024*4 dwords
    _Float16*  xg   = (_Float16*)(whhL + WLDS * 1024 * 4);  // 64*1024*1024 halves

    (void)hipFuncSetAttribute((const void*)lstm_kernel,
                              hipFuncAttributeMaxDynamicSharedMemorySize, SM_SIZE);

    pack_weights<<<1024, 128, 0, stream>>>(w_ih, w_hh, whhR, whhS, whhL, wihT);
    prep_conv_w<<<96, 256, 0, stream>>>(conv_w, wc2);
    norm_partial<<<dim3(B_N, NCHUNK), FIN, 0, stream>>>(input, part);
    conv_relu<<<dim3(B_N, 64), 256, 0, stream>>>(input, part, wc2, conv_b, X);
    x_gemm<<<dim3(B_N, 64), 256, 0, stream>>>(X, wihT, b_ih, b_hh, xg);
    lstm_kernel<<<B_N, 512, SM_SIZE, stream>>>(
        (const u32x4*)whhR, (const u32x4*)whhS, (const u32x4*)whhL, xg,
        hx0, cx0, lin_w, lin_b, (float*)d_out);
}